// Round 1
// baseline (299.514 us; speedup 1.0000x reference)
//
#include <hip/hip_runtime.h>
#include <hip/hip_bf16.h>

#define NPD 30000        // atoms per degree bucket
#define NF  128          // feature dim == filter dim
#define MAXDEG 6
#define LDK2 264         // padded K=256 LDS leading dim (bf16 elems): 528 B row stride
                         // bank advance/row = 132 % 32 = 4 -> only 2-way aliasing (free)

typedef __attribute__((ext_vector_type(8))) short short8;   // 8 x bf16 (4 VGPRs)
typedef __attribute__((ext_vector_type(4))) float floatx4;  // MFMA accumulator

__device__ __forceinline__ unsigned short f2bf(float f) {
    __hip_bfloat16 h = __float2bfloat16(f);
    return __builtin_bit_cast(unsigned short, h);
}
__device__ __forceinline__ uint4 pack16B(float4 a, float4 b) {
    uint4 v;
    v.x = (unsigned)f2bf(a.x) | ((unsigned)f2bf(a.y) << 16);
    v.y = (unsigned)f2bf(a.z) | ((unsigned)f2bf(a.w) << 16);
    v.z = (unsigned)f2bf(b.x) | ((unsigned)f2bf(b.y) << 16);
    v.w = (unsigned)f2bf(b.z) | ((unsigned)f2bf(b.w) << 16);
    return v;
}

// ---- W transpose tile: W[a][k][n] fp32 -> Wt[a][n][k] bf16 (one 32x32 tile) ----
__device__ __forceinline__ void wt_tile(const float* __restrict__ W,
                                        unsigned short* __restrict__ Wt,
                                        int bx, unsigned short (*t)[33]) {
    const int a  = bx >> 4;                       // 13 matrices x 16 tiles
    const int k0 = ((bx >> 2) & 3) * 32, n0 = (bx & 3) * 32;
    const int tx = threadIdx.x & 31, ty = threadIdx.x >> 5;  // 256 thr: 32x8
    const float*    Wp  = W  + (size_t)a * NF * NF;
    unsigned short* Wtp = Wt + (size_t)a * NF * NF;
#pragma unroll
    for (int i = 0; i < 32; i += 8)
        t[ty + i][tx] = f2bf(Wp[(size_t)(k0 + ty + i) * NF + (n0 + tx)]);
    __syncthreads();
#pragma unroll
    for (int i = 0; i < 32; i += 8)
        Wtp[(size_t)(n0 + ty + i) * NF + (k0 + tx)] = t[tx][ty + i];
}

// ---- gather-sum for one degree: rel[r] = sum_j atoms[adj[r][j]], bf16 out ----
// 8 threads per row, 16 fp32 cols each -> 4 independent float4 loads per neighbor
template <int DEG>
__device__ __forceinline__ void gather_work(const float* __restrict__ atoms,
                                            const int* __restrict__ adj,
                                            unsigned short* __restrict__ relbuf) {
    const int t = threadIdx.x;
    const int r = blockIdx.x * 32 + (t >> 3);
    if (r >= NPD) return;
    const int c = (t & 7) * 16;
    const int* arow = adj + (size_t)r * DEG;
    int idxs[DEG];
#pragma unroll
    for (int j = 0; j < DEG; ++j) idxs[j] = arow[j];
    float s[16];
#pragma unroll
    for (int i = 0; i < 16; ++i) s[i] = 0.f;
#pragma unroll
    for (int j = 0; j < DEG; ++j) {
        const float4* p = (const float4*)(atoms + (size_t)idxs[j] * NF + c);
        float4 q0 = p[0], q1 = p[1], q2 = p[2], q3 = p[3];
        s[0]  += q0.x; s[1]  += q0.y; s[2]  += q0.z; s[3]  += q0.w;
        s[4]  += q1.x; s[5]  += q1.y; s[6]  += q1.z; s[7]  += q1.w;
        s[8]  += q2.x; s[9]  += q2.y; s[10] += q2.z; s[11] += q2.w;
        s[12] += q3.x; s[13] += q3.y; s[14] += q3.z; s[15] += q3.w;
    }
    uint4 w0 = pack16B(make_float4(s[0], s[1], s[2], s[3]),
                       make_float4(s[4], s[5], s[6], s[7]));
    uint4 w1 = pack16B(make_float4(s[8], s[9], s[10], s[11]),
                       make_float4(s[12], s[13], s[14], s[15]));
    unsigned short* op = relbuf + ((size_t)(DEG - 1) * NPD + r) * NF + c;
    *(uint4*)op       = w0;
    *(uint4*)(op + 8) = w1;
}

__global__ __launch_bounds__(256) void gather_kernel(
    const float* __restrict__ atoms, const float* __restrict__ W,
    unsigned short* __restrict__ Wt,
    const int* __restrict__ adj1, const int* __restrict__ adj2,
    const int* __restrict__ adj3, const int* __restrict__ adj4,
    const int* __restrict__ adj5, const int* __restrict__ adj6,
    unsigned short* __restrict__ relbuf)
{
    __shared__ unsigned short t[32][33];     // only used by the wt slice (2.1 KB)
    if (blockIdx.y == 6) {                   // spare slice: W transpose (208 tiles)
        if (blockIdx.x < 208) wt_tile(W, Wt, blockIdx.x, t);
        return;
    }
    switch (blockIdx.y) {
        case 0: gather_work<1>(atoms, adj1, relbuf); break;
        case 1: gather_work<2>(atoms, adj2, relbuf); break;
        case 2: gather_work<3>(atoms, adj3, relbuf); break;
        case 3: gather_work<4>(atoms, adj4, relbuf); break;
        case 4: gather_work<5>(atoms, adj5, relbuf); break;
        default: gather_work<6>(atoms, adj6, relbuf); break;
    }
}

// ---- streaming K=256 GEMM: out = [self | rel] @ [Wself ; Wrel] + biases ----
// 32-row tile, 4 waves each owning 32 cols; single barrier; 100% occupancy
template <int DEG>
__device__ __forceinline__ void gemm_work(
    const float* __restrict__ atomsF, const unsigned short* __restrict__ relbuf,
    const unsigned short* __restrict__ Wt, const float* __restrict__ bvec,
    float* __restrict__ out, unsigned short* __restrict__ sA)
{
    const int tid  = threadIdx.x;
    const int lane = tid & 63, wave = tid >> 6;
    const int nb = lane & 15;
    const int kq = (lane >> 4) * 8;
    const int col0 = wave * 32;
    const int row0_local = blockIdx.x * 32;
    const int valid = min(32, NPD - row0_local);
    const int row0g = DEG * NPD + row0_local;
    const int wi_self = (DEG == 0) ? 12 : (2 * DEG - 1);
    const int wi_rel  = (DEG > 0) ? 2 * (DEG - 1) : 0;

    floatx4 acc[2][2];
#pragma unroll
    for (int i = 0; i < 2; i++)
#pragma unroll
        for (int j = 0; j < 2; j++) acc[i][j] = (floatx4){0.f, 0.f, 0.f, 0.f};

    // stage self rows -> sA cols [0,128)  (fp32 read, bf16 pack; coalesced)
#pragma unroll
    for (int p = 0; p < 2; ++p) {
        int idx = p * 256 + tid;
        int r = idx >> 4, ch = (idx & 15) * 8;
        int rr = min(r, valid - 1);
        const float4* pf = (const float4*)(atomsF + (size_t)(row0g + rr) * NF + ch);
        *(uint4*)&sA[r * LDK2 + ch] = pack16B(pf[0], pf[1]);
    }
    // stage rel rows -> sA cols [128,256)  (bf16 direct copy)
    if constexpr (DEG > 0) {
#pragma unroll
        for (int p = 0; p < 2; ++p) {
            int idx = p * 256 + tid;
            int r = idx >> 4, ch = (idx & 15) * 8;
            int rr = min(r, valid - 1);
            *(uint4*)&sA[r * LDK2 + NF + ch] =
                *(const uint4*)(relbuf + ((size_t)(DEG - 1) * NPD + row0_local + rr) * NF + ch);
        }
    }
    __syncthreads();

    // single K=256 (K=128 for deg 0) MFMA pass
    constexpr int NKK = (DEG > 0) ? 8 : 4;
#pragma unroll
    for (int kk = 0; kk < NKK; ++kk) {
        const int wi = (kk < 4) ? wi_self : wi_rel;
        const unsigned short* Wp = Wt + (size_t)wi * NF * NF;
        short8 bfr[2];
#pragma unroll
        for (int nt = 0; nt < 2; ++nt)
            bfr[nt] = *(const short8*)(Wp + (size_t)(col0 + nt * 16 + nb) * NF
                                          + (kk & 3) * 32 + kq);
        short8 af[2];
#pragma unroll
        for (int mt = 0; mt < 2; ++mt)
            af[mt] = *(const short8*)&sA[(mt * 16 + nb) * LDK2 + kk * 32 + kq];
#pragma unroll
        for (int mt = 0; mt < 2; ++mt)
#pragma unroll
            for (int nt = 0; nt < 2; ++nt)
                acc[mt][nt] = __builtin_amdgcn_mfma_f32_16x16x32_bf16(
                    af[mt], bfr[nt], acc[mt][nt], 0, 0, 0);
    }

    // epilogue: bias + fp32 store
    float bias[2];
#pragma unroll
    for (int nt = 0; nt < 2; ++nt) {
        const int n = col0 + nt * 16 + nb;
        float bv = bvec[wi_self * NF + n];
        if (DEG > 0) bv += bvec[wi_rel * NF + n];
        bias[nt] = bv;
    }
    const int rq = (lane >> 4) * 4;
#pragma unroll
    for (int mt = 0; mt < 2; ++mt) {
#pragma unroll
        for (int reg = 0; reg < 4; ++reg) {
            const int r = mt * 16 + rq + reg;
            if (r < valid) {
                float* op = out + (size_t)(row0g + r) * NF;
#pragma unroll
                for (int nt = 0; nt < 2; ++nt)
                    op[col0 + nt * 16 + nb] = acc[mt][nt][reg] + bias[nt];
            }
        }
    }
}

__global__ __launch_bounds__(256) void gemm_kernel(
    const float* __restrict__ atomsF, const unsigned short* __restrict__ relbuf,
    const unsigned short* __restrict__ Wt, const float* __restrict__ bvec,
    float* __restrict__ out)
{
    __shared__ unsigned short sA[32 * LDK2];   // 16896 B -> 8 blocks/CU, 32 waves/CU
    switch (blockIdx.y) {
        case 0: gemm_work<0>(atomsF, relbuf, Wt, bvec, out, sA); break;
        case 1: gemm_work<1>(atomsF, relbuf, Wt, bvec, out, sA); break;
        case 2: gemm_work<2>(atomsF, relbuf, Wt, bvec, out, sA); break;
        case 3: gemm_work<3>(atomsF, relbuf, Wt, bvec, out, sA); break;
        case 4: gemm_work<4>(atomsF, relbuf, Wt, bvec, out, sA); break;
        case 5: gemm_work<5>(atomsF, relbuf, Wt, bvec, out, sA); break;
        default: gemm_work<6>(atomsF, relbuf, Wt, bvec, out, sA); break;
    }
}

// ---- correctness fallback (tiny/absent workspace): fp32 exact, slow ----
__global__ __launch_bounds__(128) void naive_kernel(
    const float* __restrict__ atoms, const float* __restrict__ W,
    const float* __restrict__ b,
    const int* __restrict__ adj1, const int* __restrict__ adj2,
    const int* __restrict__ adj3, const int* __restrict__ adj4,
    const int* __restrict__ adj5, const int* __restrict__ adj6,
    float* __restrict__ out)
{
    const int i = blockIdx.x;
    const int deg = i / NPD, r = i - deg * NPD, n = threadIdx.x;
    __shared__ float selfr[NF], relr[NF];
    selfr[n] = atoms[(size_t)i * NF + n];
    float rv = 0.f;
    if (deg > 0) {
        const int* adjs[6] = {adj1, adj2, adj3, adj4, adj5, adj6};
        const int* adj = adjs[deg - 1];
        for (int j = 0; j < deg; ++j)
            rv += atoms[(size_t)adj[(size_t)r * deg + j] * NF + n];
    }
    relr[n] = rv;
    __syncthreads();
    const int ws  = (deg == 0) ? 12 : 2 * deg - 1;
    const int wrl = 2 * (deg - 1);
    float acc = b[ws * NF + n] + ((deg > 0) ? b[wrl * NF + n] : 0.f);
    for (int k = 0; k < NF; ++k) {
        acc += selfr[k] * W[(size_t)ws * NF * NF + (size_t)k * NF + n];
        if (deg > 0) acc += relr[k] * W[(size_t)wrl * NF * NF + (size_t)k * NF + n];
    }
    out[(size_t)i * NF + n] = acc;
}

extern "C" void kernel_launch(void* const* d_in, const int* in_sizes, int n_in,
                              void* d_out, int out_size, void* d_ws, size_t ws_size,
                              hipStream_t stream) {
    const float* atoms = (const float*)d_in[0];
    const float* W     = (const float*)d_in[1];
    const float* b     = (const float*)d_in[2];
    // d_in[3] = deg_slice (static, unused)
    const int* adj1 = (const int*)d_in[4];
    const int* adj2 = (const int*)d_in[5];
    const int* adj3 = (const int*)d_in[6];
    const int* adj4 = (const int*)d_in[7];
    const int* adj5 = (const int*)d_in[8];
    const int* adj6 = (const int*)d_in[9];

    const size_t wt_bytes  = (size_t)13 * NF * NF * sizeof(unsigned short);       // 425,984 (16B-mult)
    const size_t rel_bytes = (size_t)6 * NPD * NF * sizeof(unsigned short);       // 46.08 MB

    if (ws_size >= wt_bytes + rel_bytes) {
        unsigned short* Wt     = (unsigned short*)d_ws;
        unsigned short* relbuf = (unsigned short*)((char*)d_ws + wt_bytes);
        const int gx = (NPD + 31) / 32;   // 938
        // gather (+ W transpose in the 7th y-slice), then streaming GEMM
        gather_kernel<<<dim3(gx, 7), 256, 0, stream>>>(
            atoms, W, Wt, adj1, adj2, adj3, adj4, adj5, adj6, relbuf);
        gemm_kernel<<<dim3(gx, 7), 256, 0, stream>>>(atoms, relbuf, Wt, b,
                                                     (float*)d_out);
    } else {
        naive_kernel<<<NPD * (MAXDEG + 1), NF, 0, stream>>>(
            atoms, W, b, adj1, adj2, adj3, adj4, adj5, adj6, (float*)d_out);
    }
}

// Round 2
// 269.616 us; speedup vs baseline: 1.1109x; 1.1109x over previous
//
#include <hip/hip_runtime.h>
#include <hip/hip_bf16.h>

#define NPD 30000        // atoms per degree bucket
#define NF  128          // feature dim == filter dim
#define MAXDEG 6
#define LDK2 264         // padded K=256 LDS leading dim (bf16): 528 B row stride
                         // row bank advance = 132 % 32 = 4 -> only 2-way aliasing (free)

typedef __attribute__((ext_vector_type(8))) short short8;   // 8 x bf16 (4 VGPRs)
typedef __attribute__((ext_vector_type(4))) float floatx4;  // MFMA accumulator

__device__ __forceinline__ unsigned short f2bf(float f) {
    __hip_bfloat16 h = __float2bfloat16(f);
    return __builtin_bit_cast(unsigned short, h);
}
__device__ __forceinline__ uint4 pack16B(float4 a, float4 b) {
    uint4 v;
    v.x = (unsigned)f2bf(a.x) | ((unsigned)f2bf(a.y) << 16);
    v.y = (unsigned)f2bf(a.z) | ((unsigned)f2bf(a.w) << 16);
    v.z = (unsigned)f2bf(b.x) | ((unsigned)f2bf(b.y) << 16);
    v.w = (unsigned)f2bf(b.z) | ((unsigned)f2bf(b.w) << 16);
    return v;
}

// ---- W transpose: W[a][k][n] fp32 -> Wt[a][n][k] bf16 (208 x 32x32 tiles) ----
__global__ __launch_bounds__(256) void wt_kernel(const float* __restrict__ W,
                                                 unsigned short* __restrict__ Wt) {
    __shared__ unsigned short t[32][33];
    const int bx = blockIdx.x;                    // 13 matrices x 16 tiles
    const int a  = bx >> 4;
    const int k0 = ((bx >> 2) & 3) * 32, n0 = (bx & 3) * 32;
    const int tx = threadIdx.x & 31, ty = threadIdx.x >> 5;  // 256 thr: 32x8
    const float*    Wp  = W  + (size_t)a * NF * NF;
    unsigned short* Wtp = Wt + (size_t)a * NF * NF;
#pragma unroll
    for (int i = 0; i < 32; i += 8)
        t[ty + i][tx] = f2bf(Wp[(size_t)(k0 + ty + i) * NF + (n0 + tx)]);
    __syncthreads();
#pragma unroll
    for (int i = 0; i < 32; i += 8)
        Wtp[(size_t)(n0 + ty + i) * NF + (k0 + tx)] = t[tx][ty + i];
}

// ---- fused: gather(LDS) + self(LDS) -> K=256 MFMA -> nontemporal store ----
template <int DEG>
__device__ __forceinline__ void fused_work(
    const float* __restrict__ atoms, const unsigned short* __restrict__ Wt,
    const float* __restrict__ bvec, const int* __restrict__ adj,
    float* __restrict__ out, unsigned short* __restrict__ sA)
{
    const int tid  = threadIdx.x;
    const int lane = tid & 63, wave = tid >> 6;
    const int nb = lane & 15;
    const int kq = (lane >> 4) * 8;
    const int col0 = wave * 32;
    const int row0 = blockIdx.x * 32;
    const int valid = min(32, NPD - row0);
    const int row0g = DEG * NPD + row0;
    const int wi_self = (DEG == 0) ? 12 : (2 * DEG - 1);
    const int wi_rel  = (DEG > 0) ? 2 * (DEG - 1) : 0;

    // ---- issue self-stage loads FIRST (oldest in vmcnt queue) ----
    // 512 chunks of 8 fp32 cols: thread covers chunk tid (rows 0-15) and tid+256
    const int r0 = tid >> 4,          ch0 = (tid & 15) * 8;
    const int r1 = (tid >> 4) + 16,   ch1 = ch0;
    const int rr0 = min(r0, valid - 1), rr1 = min(r1, valid - 1);
    const float4* sp0 = (const float4*)(atoms + (size_t)(row0g + rr0) * NF + ch0);
    const float4* sp1 = (const float4*)(atoms + (size_t)(row0g + rr1) * NF + ch1);
    float4 sv0 = sp0[0], sv1 = sp0[1], sv2 = sp1[0], sv3 = sp1[1];

    if constexpr (DEG > 0) {
        // ---- gather: 8 thr/row, 16 fp32 cols each ----
        const int gr  = tid >> 3;                 // 0..31
        const int gc  = (tid & 7) * 16;
        const int grr = min(gr, valid - 1);
        const int* arow = adj + (size_t)(row0 + grr) * DEG;
        int idxs[DEG];
#pragma unroll
        for (int j = 0; j < DEG; ++j) idxs[j] = arow[j];

        // self pack+write while gather idx/first loads are in flight
        *(uint4*)&sA[r0 * LDK2 + ch0] = pack16B(sv0, sv1);
        *(uint4*)&sA[r1 * LDK2 + ch1] = pack16B(sv2, sv3);

        float s[16];
#pragma unroll
        for (int i = 0; i < 16; ++i) s[i] = 0.f;
        // 2-deep software pipeline over neighbors
        float4 q0, q1, q2, q3, n0, n1, n2, n3;
        {
            const float4* p = (const float4*)(atoms + (size_t)idxs[0] * NF + gc);
            q0 = p[0]; q1 = p[1]; q2 = p[2]; q3 = p[3];
        }
#pragma unroll
        for (int j = 0; j < DEG; ++j) {
            if (j + 1 < DEG) {
                const float4* p = (const float4*)(atoms + (size_t)idxs[j + 1] * NF + gc);
                n0 = p[0]; n1 = p[1]; n2 = p[2]; n3 = p[3];
            }
            s[0]  += q0.x; s[1]  += q0.y; s[2]  += q0.z; s[3]  += q0.w;
            s[4]  += q1.x; s[5]  += q1.y; s[6]  += q1.z; s[7]  += q1.w;
            s[8]  += q2.x; s[9]  += q2.y; s[10] += q2.z; s[11] += q2.w;
            s[12] += q3.x; s[13] += q3.y; s[14] += q3.z; s[15] += q3.w;
            q0 = n0; q1 = n1; q2 = n2; q3 = n3;
        }
        uint4 w0 = pack16B(make_float4(s[0], s[1], s[2], s[3]),
                           make_float4(s[4], s[5], s[6], s[7]));
        uint4 w1 = pack16B(make_float4(s[8], s[9], s[10], s[11]),
                           make_float4(s[12], s[13], s[14], s[15]));
        *(uint4*)&sA[gr * LDK2 + NF + gc]     = w0;
        *(uint4*)&sA[gr * LDK2 + NF + gc + 8] = w1;
    } else {
        *(uint4*)&sA[r0 * LDK2 + ch0] = pack16B(sv0, sv1);
        *(uint4*)&sA[r1 * LDK2 + ch1] = pack16B(sv2, sv3);
    }
    __syncthreads();

    // ---- single K=256 (K=128 for deg 0) MFMA pass ----
    floatx4 acc[2][2];
#pragma unroll
    for (int i = 0; i < 2; i++)
#pragma unroll
        for (int j = 0; j < 2; j++) acc[i][j] = (floatx4){0.f, 0.f, 0.f, 0.f};

    constexpr int NKK = (DEG > 0) ? 8 : 4;
#pragma unroll
    for (int kk = 0; kk < NKK; ++kk) {
        const int wi = (kk < 4) ? wi_self : wi_rel;
        const unsigned short* Wp = Wt + (size_t)wi * NF * NF;
        short8 bfr[2];
#pragma unroll
        for (int nt = 0; nt < 2; ++nt)
            bfr[nt] = *(const short8*)(Wp + (size_t)(col0 + nt * 16 + nb) * NF
                                          + (kk & 3) * 32 + kq);
        short8 af[2];
#pragma unroll
        for (int mt = 0; mt < 2; ++mt)
            af[mt] = *(const short8*)&sA[(mt * 16 + nb) * LDK2 + kk * 32 + kq];
#pragma unroll
        for (int mt = 0; mt < 2; ++mt)
#pragma unroll
            for (int nt = 0; nt < 2; ++nt)
                acc[mt][nt] = __builtin_amdgcn_mfma_f32_16x16x32_bf16(
                    af[mt], bfr[nt], acc[mt][nt], 0, 0, 0);
    }

    // ---- epilogue: bias + nontemporal fp32 store (keep atoms in L3) ----
    float bias[2];
#pragma unroll
    for (int nt = 0; nt < 2; ++nt) {
        const int n = col0 + nt * 16 + nb;
        float bv = bvec[wi_self * NF + n];
        if (DEG > 0) bv += bvec[wi_rel * NF + n];
        bias[nt] = bv;
    }
    const int rq = (lane >> 4) * 4;
#pragma unroll
    for (int mt = 0; mt < 2; ++mt) {
#pragma unroll
        for (int reg = 0; reg < 4; ++reg) {
            const int r = mt * 16 + rq + reg;
            if (r < valid) {
                float* op = out + (size_t)(row0g + r) * NF;
#pragma unroll
                for (int nt = 0; nt < 2; ++nt)
                    __builtin_nontemporal_store(acc[mt][nt][reg] + bias[nt],
                                                op + col0 + nt * 16 + nb);
            }
        }
    }
}

__global__ __launch_bounds__(256) void fused_kernel(
    const float* __restrict__ atoms, const unsigned short* __restrict__ Wt,
    const float* __restrict__ bvec,
    const int* __restrict__ adj1, const int* __restrict__ adj2,
    const int* __restrict__ adj3, const int* __restrict__ adj4,
    const int* __restrict__ adj5, const int* __restrict__ adj6,
    float* __restrict__ out)
{
    __shared__ unsigned short sA[32 * LDK2];   // 16896 B
    switch (blockIdx.y) {
        case 0: fused_work<0>(atoms, Wt, bvec, nullptr, out, sA); break;
        case 1: fused_work<1>(atoms, Wt, bvec, adj1,    out, sA); break;
        case 2: fused_work<2>(atoms, Wt, bvec, adj2,    out, sA); break;
        case 3: fused_work<3>(atoms, Wt, bvec, adj3,    out, sA); break;
        case 4: fused_work<4>(atoms, Wt, bvec, adj4,    out, sA); break;
        case 5: fused_work<5>(atoms, Wt, bvec, adj5,    out, sA); break;
        default: fused_work<6>(atoms, Wt, bvec, adj6,   out, sA); break;
    }
}

// ---- correctness fallback (tiny/absent workspace): fp32 exact, slow ----
__global__ __launch_bounds__(128) void naive_kernel(
    const float* __restrict__ atoms, const float* __restrict__ W,
    const float* __restrict__ b,
    const int* __restrict__ adj1, const int* __restrict__ adj2,
    const int* __restrict__ adj3, const int* __restrict__ adj4,
    const int* __restrict__ adj5, const int* __restrict__ adj6,
    float* __restrict__ out)
{
    const int i = blockIdx.x;
    const int deg = i / NPD, r = i - deg * NPD, n = threadIdx.x;
    __shared__ float selfr[NF], relr[NF];
    selfr[n] = atoms[(size_t)i * NF + n];
    float rv = 0.f;
    if (deg > 0) {
        const int* adjs[6] = {adj1, adj2, adj3, adj4, adj5, adj6};
        const int* adj = adjs[deg - 1];
        for (int j = 0; j < deg; ++j)
            rv += atoms[(size_t)adj[(size_t)r * deg + j] * NF + n];
    }
    relr[n] = rv;
    __syncthreads();
    const int ws  = (deg == 0) ? 12 : 2 * deg - 1;
    const int wrl = 2 * (deg - 1);
    float acc = b[ws * NF + n] + ((deg > 0) ? b[wrl * NF + n] : 0.f);
    for (int k = 0; k < NF; ++k) {
        acc += selfr[k] * W[(size_t)ws * NF * NF + (size_t)k * NF + n];
        if (deg > 0) acc += relr[k] * W[(size_t)wrl * NF * NF + (size_t)k * NF + n];
    }
    out[(size_t)i * NF + n] = acc;
}

extern "C" void kernel_launch(void* const* d_in, const int* in_sizes, int n_in,
                              void* d_out, int out_size, void* d_ws, size_t ws_size,
                              hipStream_t stream) {
    const float* atoms = (const float*)d_in[0];
    const float* W     = (const float*)d_in[1];
    const float* b     = (const float*)d_in[2];
    // d_in[3] = deg_slice (static, unused)
    const int* adj1 = (const int*)d_in[4];
    const int* adj2 = (const int*)d_in[5];
    const int* adj3 = (const int*)d_in[6];
    const int* adj4 = (const int*)d_in[7];
    const int* adj5 = (const int*)d_in[8];
    const int* adj6 = (const int*)d_in[9];

    const size_t wt_bytes = (size_t)13 * NF * NF * sizeof(unsigned short);  // 425,984

    if (ws_size >= wt_bytes) {
        unsigned short* Wt = (unsigned short*)d_ws;
        wt_kernel<<<208, 256, 0, stream>>>(W, Wt);
        const int gx = (NPD + 31) / 32;   // 938
        fused_kernel<<<dim3(gx, 7), 256, 0, stream>>>(
            atoms, Wt, b, adj1, adj2, adj3, adj4, adj5, adj6, (float*)d_out);
    } else {
        naive_kernel<<<NPD * (MAXDEG + 1), NF, 0, stream>>>(
            atoms, W, b, adj1, adj2, adj3, adj4, adj5, adj6, (float*)d_out);
    }
}

// Round 4
// 264.706 us; speedup vs baseline: 1.1315x; 1.0185x over previous
//
#include <hip/hip_runtime.h>
#include <hip/hip_bf16.h>

#define NPD 30000        // atoms per degree bucket
#define NF  128          // feature dim == filter dim
#define MAXDEG 6
#define LDK2 264         // padded K=256 LDS leading dim (bf16): 528 B row stride

#define CVT_BLOCKS 13125 // 210000*128/8 / 256
#define WT_BLOCKS  208   // 13 matrices x 16 (32x32) tiles

typedef __attribute__((ext_vector_type(8))) short short8;   // 8 x bf16 (4 VGPRs)
typedef __attribute__((ext_vector_type(4))) float floatx4;  // MFMA accumulator / NT loads

__device__ __forceinline__ unsigned short f2bf(float f) {
    __hip_bfloat16 h = __float2bfloat16(f);
    return __builtin_bit_cast(unsigned short, h);
}
__device__ __forceinline__ float bf2f(unsigned short u) {
    unsigned v = ((unsigned)u) << 16; return __builtin_bit_cast(float, v);
}
__device__ __forceinline__ uint4 pack16B(float4 a, float4 b) {
    uint4 v;
    v.x = (unsigned)f2bf(a.x) | ((unsigned)f2bf(a.y) << 16);
    v.y = (unsigned)f2bf(a.z) | ((unsigned)f2bf(a.w) << 16);
    v.z = (unsigned)f2bf(b.x) | ((unsigned)f2bf(b.y) << 16);
    v.w = (unsigned)f2bf(b.z) | ((unsigned)f2bf(b.w) << 16);
    return v;
}
__device__ __forceinline__ uint4 pack16Bv(floatx4 a, floatx4 b) {
    uint4 v;
    v.x = (unsigned)f2bf(a.x) | ((unsigned)f2bf(a.y) << 16);
    v.y = (unsigned)f2bf(a.z) | ((unsigned)f2bf(a.w) << 16);
    v.z = (unsigned)f2bf(b.x) | ((unsigned)f2bf(b.y) << 16);
    v.w = (unsigned)f2bf(b.z) | ((unsigned)f2bf(b.w) << 16);
    return v;
}
__device__ __forceinline__ void addu4(float* s, uint4 h) {
    s[0] += bf2f((unsigned short)h.x); s[1] += bf2f((unsigned short)(h.x >> 16));
    s[2] += bf2f((unsigned short)h.y); s[3] += bf2f((unsigned short)(h.y >> 16));
    s[4] += bf2f((unsigned short)h.z); s[5] += bf2f((unsigned short)(h.z >> 16));
    s[6] += bf2f((unsigned short)h.w); s[7] += bf2f((unsigned short)(h.w >> 16));
}

// ---- prep: wt tiles (bx < 208) + fp32->bf16 atoms mirror (bx >= 208) ----
// nontemporal fp32 loads: the fp32 atoms are dead after this pass in the bf16
// path -- keep them out of L3 so the mirror + streams own it.
__global__ __launch_bounds__(256) void prep_kernel(
    const float* __restrict__ atoms, const float* __restrict__ W,
    unsigned short* __restrict__ atomsH, unsigned short* __restrict__ Wt)
{
    __shared__ unsigned short t[32][33];
    const int bx = blockIdx.x;
    if (bx < WT_BLOCKS) {                         // W[a][k][n] -> Wt[a][n][k] bf16
        const int a  = bx >> 4;
        const int k0 = ((bx >> 2) & 3) * 32, n0 = (bx & 3) * 32;
        const int tx = threadIdx.x & 31, ty = threadIdx.x >> 5;
        const float*    Wp  = W  + (size_t)a * NF * NF;
        unsigned short* Wtp = Wt + (size_t)a * NF * NF;
#pragma unroll
        for (int i = 0; i < 32; i += 8)
            t[ty + i][tx] = f2bf(Wp[(size_t)(k0 + ty + i) * NF + (n0 + tx)]);
        __syncthreads();
#pragma unroll
        for (int i = 0; i < 32; i += 8)
            Wtp[(size_t)(n0 + ty + i) * NF + (k0 + tx)] = t[tx][ty + i];
    } else {
        const size_t i = (size_t)(bx - WT_BLOCKS) * 256 + threadIdx.x;  // one uint4 out
        const floatx4* p = (const floatx4*)(atoms + i * 8);
        floatx4 a = __builtin_nontemporal_load(p);
        floatx4 b = __builtin_nontemporal_load(p + 1);
        ((uint4*)atomsH)[i] = pack16Bv(a, b);
    }
}

// ---- fused: gather(LDS) + self(LDS) -> K=256 MFMA -> nontemporal store ----
template <int DEG, bool BF16A>
__device__ __forceinline__ void fused_work(
    const float* __restrict__ atomsF, const unsigned short* __restrict__ atomsH,
    const unsigned short* __restrict__ Wt, const float* __restrict__ bvec,
    const int* __restrict__ adj, float* __restrict__ out,
    unsigned short* __restrict__ sA)
{
    const int tid  = threadIdx.x;
    const int lane = tid & 63, wave = tid >> 6;
    const int nb = lane & 15;
    const int kq = (lane >> 4) * 8;
    const int col0 = wave * 32;
    const int row0 = blockIdx.x * 32;
    const int valid = min(32, NPD - row0);
    const int row0g = DEG * NPD + row0;
    const int wi_self = (DEG == 0) ? 12 : (2 * DEG - 1);
    const int wi_rel  = (DEG > 0) ? 2 * (DEG - 1) : 0;

    // ---- self-stage: 512 chunks of 8 cols; thread covers chunk tid and tid+256
    const int r0 = tid >> 4,        ch0 = (tid & 15) * 8;
    const int r1 = r0 + 16;
    const int rr0 = min(r0, valid - 1), rr1 = min(r1, valid - 1);
    if (BF16A) {
        uint4 s0 = *(const uint4*)(atomsH + (size_t)(row0g + rr0) * NF + ch0);
        uint4 s1 = *(const uint4*)(atomsH + (size_t)(row0g + rr1) * NF + ch0);
        *(uint4*)&sA[r0 * LDK2 + ch0] = s0;
        *(uint4*)&sA[r1 * LDK2 + ch0] = s1;
    } else {
        const float4* sp0 = (const float4*)(atomsF + (size_t)(row0g + rr0) * NF + ch0);
        const float4* sp1 = (const float4*)(atomsF + (size_t)(row0g + rr1) * NF + ch0);
        float4 a0 = sp0[0], a1 = sp0[1], a2 = sp1[0], a3 = sp1[1];
        *(uint4*)&sA[r0 * LDK2 + ch0] = pack16B(a0, a1);
        *(uint4*)&sA[r1 * LDK2 + ch0] = pack16B(a2, a3);
    }

    if constexpr (DEG > 0) {
        // ---- gather: 8 thr/row, 16 cols each ----
        const int gr  = tid >> 3;                 // 0..31
        const int gc  = (tid & 7) * 16;
        const int grr = min(gr, valid - 1);
        const int* arow = adj + (size_t)(row0 + grr) * DEG;
        int idxs[DEG];
#pragma unroll
        for (int j = 0; j < DEG; ++j) idxs[j] = arow[j];

        float s[16];
#pragma unroll
        for (int i = 0; i < 16; ++i) s[i] = 0.f;

        if (BF16A) {
            // fully unrolled: all 2*DEG uint4 loads issued up front (max 12)
            uint4 ga[DEG], gb[DEG];
#pragma unroll
            for (int j = 0; j < DEG; ++j) {
                const unsigned short* base = atomsH + (size_t)idxs[j] * NF + gc;
                ga[j] = *(const uint4*)base;
                gb[j] = *(const uint4*)(base + 8);
            }
#pragma unroll
            for (int j = 0; j < DEG; ++j) {
                addu4(s, ga[j]);
                addu4(s + 8, gb[j]);
            }
        } else {
            // fp32 fallback: 2-deep software pipeline
            float4 q0, q1, q2, q3, n0, n1, n2, n3;
            {
                const float4* p = (const float4*)(atomsF + (size_t)idxs[0] * NF + gc);
                q0 = p[0]; q1 = p[1]; q2 = p[2]; q3 = p[3];
            }
#pragma unroll
            for (int j = 0; j < DEG; ++j) {
                if (j + 1 < DEG) {
                    const float4* p = (const float4*)(atomsF + (size_t)idxs[j + 1] * NF + gc);
                    n0 = p[0]; n1 = p[1]; n2 = p[2]; n3 = p[3];
                }
                s[0]  += q0.x; s[1]  += q0.y; s[2]  += q0.z; s[3]  += q0.w;
                s[4]  += q1.x; s[5]  += q1.y; s[6]  += q1.z; s[7]  += q1.w;
                s[8]  += q2.x; s[9]  += q2.y; s[10] += q2.z; s[11] += q2.w;
                s[12] += q3.x; s[13] += q3.y; s[14] += q3.z; s[15] += q3.w;
                q0 = n0; q1 = n1; q2 = n2; q3 = n3;
            }
        }
        uint4 w0 = pack16B(make_float4(s[0], s[1], s[2], s[3]),
                           make_float4(s[4], s[5], s[6], s[7]));
        uint4 w1 = pack16B(make_float4(s[8], s[9], s[10], s[11]),
                           make_float4(s[12], s[13], s[14], s[15]));
        *(uint4*)&sA[gr * LDK2 + NF + gc]     = w0;
        *(uint4*)&sA[gr * LDK2 + NF + gc + 8] = w1;
    }
    __syncthreads();

    // ---- single K=256 (K=128 for deg 0) MFMA pass ----
    floatx4 acc[2][2];
#pragma unroll
    for (int i = 0; i < 2; i++)
#pragma unroll
        for (int j = 0; j < 2; j++) acc[i][j] = (floatx4){0.f, 0.f, 0.f, 0.f};

    constexpr int NKK = (DEG > 0) ? 8 : 4;
#pragma unroll
    for (int kk = 0; kk < NKK; ++kk) {
        const int wi = (kk < 4) ? wi_self : wi_rel;
        const unsigned short* Wp = Wt + (size_t)wi * NF * NF;
        short8 bfr[2];
#pragma unroll
        for (int nt = 0; nt < 2; ++nt)
            bfr[nt] = *(const short8*)(Wp + (size_t)(col0 + nt * 16 + nb) * NF
                                          + (kk & 3) * 32 + kq);
        short8 af[2];
#pragma unroll
        for (int mt = 0; mt < 2; ++mt)
            af[mt] = *(const short8*)&sA[(mt * 16 + nb) * LDK2 + kk * 32 + kq];
#pragma unroll
        for (int mt = 0; mt < 2; ++mt)
#pragma unroll
            for (int nt = 0; nt < 2; ++nt)
                acc[mt][nt] = __builtin_amdgcn_mfma_f32_16x16x32_bf16(
                    af[mt], bfr[nt], acc[mt][nt], 0, 0, 0);
    }

    // ---- epilogue: bias + nontemporal fp32 store (keep mirror in L3) ----
    float bias[2];
#pragma unroll
    for (int nt = 0; nt < 2; ++nt) {
        const int n = col0 + nt * 16 + nb;
        float bv = bvec[wi_self * NF + n];
        if (DEG > 0) bv += bvec[wi_rel * NF + n];
        bias[nt] = bv;
    }
    const int rq = (lane >> 4) * 4;
#pragma unroll
    for (int mt = 0; mt < 2; ++mt) {
#pragma unroll
        for (int reg = 0; reg < 4; ++reg) {
            const int r = mt * 16 + rq + reg;
            if (r < valid) {
                float* op = out + (size_t)(row0g + r) * NF;
#pragma unroll
                for (int nt = 0; nt < 2; ++nt)
                    __builtin_nontemporal_store(acc[mt][nt][reg] + bias[nt],
                                                op + col0 + nt * 16 + nb);
            }
        }
    }
}

template <bool BF16A>
__global__ __launch_bounds__(256) void fused_kernel(
    const float* __restrict__ atomsF, const unsigned short* __restrict__ atomsH,
    const unsigned short* __restrict__ Wt, const float* __restrict__ bvec,
    const int* __restrict__ adj1, const int* __restrict__ adj2,
    const int* __restrict__ adj3, const int* __restrict__ adj4,
    const int* __restrict__ adj5, const int* __restrict__ adj6,
    float* __restrict__ out)
{
    __shared__ unsigned short sA[32 * LDK2];   // 16896 B
    switch (blockIdx.y) {
        case 0: fused_work<0, BF16A>(atomsF, atomsH, Wt, bvec, nullptr, out, sA); break;
        case 1: fused_work<1, BF16A>(atomsF, atomsH, Wt, bvec, adj1,    out, sA); break;
        case 2: fused_work<2, BF16A>(atomsF, atomsH, Wt, bvec, adj2,    out, sA); break;
        case 3: fused_work<3, BF16A>(atomsF, atomsH, Wt, bvec, adj3,    out, sA); break;
        case 4: fused_work<4, BF16A>(atomsF, atomsH, Wt, bvec, adj4,    out, sA); break;
        case 5: fused_work<5, BF16A>(atomsF, atomsH, Wt, bvec, adj5,    out, sA); break;
        default: fused_work<6, BF16A>(atomsF, atomsH, Wt, bvec, adj6,   out, sA); break;
    }
}

// ---- correctness fallback (tiny/absent workspace): fp32 exact, slow ----
__global__ __launch_bounds__(128) void naive_kernel(
    const float* __restrict__ atoms, const float* __restrict__ W,
    const float* __restrict__ b,
    const int* __restrict__ adj1, const int* __restrict__ adj2,
    const int* __restrict__ adj3, const int* __restrict__ adj4,
    const int* __restrict__ adj5, const int* __restrict__ adj6,
    float* __restrict__ out)
{
    const int i = blockIdx.x;
    const int deg = i / NPD, r = i - deg * NPD, n = threadIdx.x;
    __shared__ float selfr[NF], relr[NF];
    selfr[n] = atoms[(size_t)i * NF + n];
    float rv = 0.f;
    if (deg > 0) {
        const int* adjs[6] = {adj1, adj2, adj3, adj4, adj5, adj6};
        const int* adj = adjs[deg - 1];
        for (int j = 0; j < deg; ++j)
            rv += atoms[(size_t)adj[(size_t)r * deg + j] * NF + n];
    }
    relr[n] = rv;
    __syncthreads();
    const int ws  = (deg == 0) ? 12 : 2 * deg - 1;
    const int wrl = 2 * (deg - 1);
    float acc = b[ws * NF + n] + ((deg > 0) ? b[wrl * NF + n] : 0.f);
    for (int k = 0; k < NF; ++k) {
        acc += selfr[k] * W[(size_t)ws * NF * NF + (size_t)k * NF + n];
        if (deg > 0) acc += relr[k] * W[(size_t)wrl * NF * NF + (size_t)k * NF + n];
    }
    out[(size_t)i * NF + n] = acc;
}

extern "C" void kernel_launch(void* const* d_in, const int* in_sizes, int n_in,
                              void* d_out, int out_size, void* d_ws, size_t ws_size,
                              hipStream_t stream) {
    const float* atoms = (const float*)d_in[0];
    const float* W     = (const float*)d_in[1];
    const float* b     = (const float*)d_in[2];
    // d_in[3] = deg_slice (static, unused)
    const int* adj1 = (const int*)d_in[4];
    const int* adj2 = (const int*)d_in[5];
    const int* adj3 = (const int*)d_in[6];
    const int* adj4 = (const int*)d_in[7];
    const int* adj5 = (const int*)d_in[8];
    const int* adj6 = (const int*)d_in[9];

    const size_t wt_bytes = (size_t)13 * NF * NF * sizeof(unsigned short);            // 425,984
    const size_t at_bytes = (size_t)NPD * (MAXDEG + 1) * NF * sizeof(unsigned short); // 53.76 MB
    const int gx = (NPD + 31) / 32;   // 938

    if (ws_size >= wt_bytes + at_bytes) {
        unsigned short* Wt     = (unsigned short*)d_ws;
        unsigned short* atomsH = (unsigned short*)((char*)d_ws + wt_bytes);
        prep_kernel<<<WT_BLOCKS + CVT_BLOCKS, 256, 0, stream>>>(atoms, W, atomsH, Wt);
        fused_kernel<true><<<dim3(gx, 7), 256, 0, stream>>>(
            atoms, atomsH, Wt, b, adj1, adj2, adj3, adj4, adj5, adj6, (float*)d_out);
    } else if (ws_size >= wt_bytes) {
        unsigned short* Wt = (unsigned short*)d_ws;
        prep_kernel<<<WT_BLOCKS, 256, 0, stream>>>(atoms, W, nullptr, Wt);  // wt only
        fused_kernel<false><<<dim3(gx, 7), 256, 0, stream>>>(
            atoms, nullptr, Wt, b, adj1, adj2, adj3, adj4, adj5, adj6, (float*)d_out);
    } else {
        naive_kernel<<<NPD * (MAXDEG + 1), NF, 0, stream>>>(
            atoms, W, b, adj1, adj2, adj3, adj4, adj5, adj6, (float*)d_out);
    }
}

// Round 5
// 264.599 us; speedup vs baseline: 1.1320x; 1.0004x over previous
//
#include <hip/hip_runtime.h>
#include <hip/hip_bf16.h>

#define NPD 30000        // atoms per degree bucket
#define NF  128          // feature dim == filter dim
#define MAXDEG 6
#define LDK2 264         // padded K=256 LDS leading dim (bf16): 528 B row stride

#define WT_BLOCKS   208  // 13 matrices x 16 (32x32) tiles
#define CVT8_BLOCKS 1641 // ceil(210000*128/8 / (256*8))

typedef __attribute__((ext_vector_type(8))) short short8;   // 8 x bf16 (4 VGPRs)
typedef __attribute__((ext_vector_type(4))) float floatx4;  // MFMA accumulator / NT loads

__device__ __forceinline__ unsigned short f2bf(float f) {
    __hip_bfloat16 h = __float2bfloat16(f);
    return __builtin_bit_cast(unsigned short, h);
}
__device__ __forceinline__ float bf2f(unsigned short u) {
    unsigned v = ((unsigned)u) << 16; return __builtin_bit_cast(float, v);
}
__device__ __forceinline__ uint4 pack16B(float4 a, float4 b) {
    uint4 v;
    v.x = (unsigned)f2bf(a.x) | ((unsigned)f2bf(a.y) << 16);
    v.y = (unsigned)f2bf(a.z) | ((unsigned)f2bf(a.w) << 16);
    v.z = (unsigned)f2bf(b.x) | ((unsigned)f2bf(b.y) << 16);
    v.w = (unsigned)f2bf(b.z) | ((unsigned)f2bf(b.w) << 16);
    return v;
}
__device__ __forceinline__ uint4 pack16Bv(floatx4 a, floatx4 b) {
    uint4 v;
    v.x = (unsigned)f2bf(a.x) | ((unsigned)f2bf(a.y) << 16);
    v.y = (unsigned)f2bf(a.z) | ((unsigned)f2bf(a.w) << 16);
    v.z = (unsigned)f2bf(b.x) | ((unsigned)f2bf(b.y) << 16);
    v.w = (unsigned)f2bf(b.z) | ((unsigned)f2bf(b.w) << 16);
    return v;
}
__device__ __forceinline__ void addu4(float* s, uint4 h) {
    s[0] += bf2f((unsigned short)h.x); s[1] += bf2f((unsigned short)(h.x >> 16));
    s[2] += bf2f((unsigned short)h.y); s[3] += bf2f((unsigned short)(h.y >> 16));
    s[4] += bf2f((unsigned short)h.z); s[5] += bf2f((unsigned short)(h.z >> 16));
    s[6] += bf2f((unsigned short)h.w); s[7] += bf2f((unsigned short)(h.w >> 16));
}

// lgkmcnt-only barrier: LDS writes visible, but global loads stay in flight
// (__syncthreads drains vmcnt(0), which would kill the gather overlap).
__device__ __forceinline__ void lgkm_barrier() {
    asm volatile("s_waitcnt lgkmcnt(0)" ::: "memory");
    __builtin_amdgcn_s_barrier();
}

// ---- prep: wt tiles (bx < 208) + fp32->bf16 atoms mirror (grid-stride x8) ----
__global__ __launch_bounds__(256) void prep_kernel(
    const float* __restrict__ atoms, const float* __restrict__ W,
    unsigned short* __restrict__ atomsH, unsigned short* __restrict__ Wt)
{
    __shared__ unsigned short t[32][33];
    const int bx = blockIdx.x;
    if (bx < WT_BLOCKS) {                         // W[a][k][n] -> Wt[a][n][k] bf16
        const int a  = bx >> 4;
        const int k0 = ((bx >> 2) & 3) * 32, n0 = (bx & 3) * 32;
        const int tx = threadIdx.x & 31, ty = threadIdx.x >> 5;
        const float*    Wp  = W  + (size_t)a * NF * NF;
        unsigned short* Wtp = Wt + (size_t)a * NF * NF;
#pragma unroll
        for (int i = 0; i < 32; i += 8)
            t[ty + i][tx] = f2bf(Wp[(size_t)(k0 + ty + i) * NF + (n0 + tx)]);
        __syncthreads();
#pragma unroll
        for (int i = 0; i < 32; i += 8)
            Wtp[(size_t)(n0 + ty + i) * NF + (k0 + tx)] = t[tx][ty + i];
    } else {
        const size_t n8   = (size_t)NPD * (MAXDEG + 1) * NF / 8;   // 3,360,000 uint4s
        const size_t base = (size_t)(bx - WT_BLOCKS) * 2048 + threadIdx.x;
#pragma unroll
        for (int it = 0; it < 8; ++it) {
            const size_t i = base + (size_t)it * 256;
            if (i < n8) {
                const floatx4* p = (const floatx4*)(atoms + i * 8);
                floatx4 a = __builtin_nontemporal_load(p);      // fp32 dead after this
                floatx4 b = __builtin_nontemporal_load(p + 1);
                ((uint4*)atomsH)[i] = pack16Bv(a, b);           // plain store: L2/L3-warm
            }
        }
    }
}

// ---- fused: self->LDS + gather-in-flight, MFMA self-half under the gather,
//      then rel-half; nontemporal fp32 store ----
template <int DEG, bool BF16A>
__device__ __forceinline__ void fused_work(
    const float* __restrict__ atomsF, const unsigned short* __restrict__ atomsH,
    const unsigned short* __restrict__ Wt, const float* __restrict__ bvec,
    const int* __restrict__ adj, float* __restrict__ out,
    unsigned short* __restrict__ sA, int bx)
{
    const int tid  = threadIdx.x;
    const int lane = tid & 63, wave = tid >> 6;
    const int nb = lane & 15;
    const int kq = (lane >> 4) * 8;
    const int col0 = wave * 32;
    const int row0 = bx * 32;
    const int valid = min(32, NPD - row0);
    const int row0g = DEG * NPD + row0;
    const int wi_self = (DEG == 0) ? 12 : (2 * DEG - 1);
    const int wi_rel  = (DEG > 0) ? 2 * (DEG - 1) : 0;

    floatx4 acc[2][2];
#pragma unroll
    for (int i = 0; i < 2; i++)
#pragma unroll
        for (int j = 0; j < 2; j++) acc[i][j] = (floatx4){0.f, 0.f, 0.f, 0.f};

    // self-stage geometry: 512 chunks of 8 cols; thread covers chunk tid, tid+256
    const int r0 = tid >> 4,  ch0 = (tid & 15) * 8;
    const int r1 = r0 + 16;
    const int rr0 = min(r0, valid - 1), rr1 = min(r1, valid - 1);

    // MFMA over 4 K-subtiles with preloaded B-fragments
    auto mma4_pre = [&](const short8 bs[4][2], int aoff) {
#pragma unroll
        for (int kk = 0; kk < 4; ++kk) {
            short8 af[2];
#pragma unroll
            for (int mt = 0; mt < 2; ++mt)
                af[mt] = *(const short8*)&sA[(mt * 16 + nb) * LDK2 + aoff + kk * 32 + kq];
#pragma unroll
            for (int mt = 0; mt < 2; ++mt)
#pragma unroll
                for (int nt = 0; nt < 2; ++nt)
                    acc[mt][nt] = __builtin_amdgcn_mfma_f32_16x16x32_bf16(
                        af[mt], bs[kk][nt], acc[mt][nt], 0, 0, 0);
        }
    };
    // MFMA over 4 K-subtiles, B-fragments loaded in-loop
    auto mma4_ld = [&](int wi, int aoff) {
        const unsigned short* Wp = Wt + (size_t)wi * NF * NF;
#pragma unroll
        for (int kk = 0; kk < 4; ++kk) {
            short8 bfr[2];
#pragma unroll
            for (int nt = 0; nt < 2; ++nt)
                bfr[nt] = *(const short8*)(Wp + (size_t)(col0 + nt * 16 + nb) * NF
                                              + kk * 32 + kq);
            short8 af[2];
#pragma unroll
            for (int mt = 0; mt < 2; ++mt)
                af[mt] = *(const short8*)&sA[(mt * 16 + nb) * LDK2 + aoff + kk * 32 + kq];
#pragma unroll
            for (int mt = 0; mt < 2; ++mt)
#pragma unroll
                for (int nt = 0; nt < 2; ++nt)
                    acc[mt][nt] = __builtin_amdgcn_mfma_f32_16x16x32_bf16(
                        af[mt], bfr[nt], acc[mt][nt], 0, 0, 0);
        }
    };

    if constexpr (BF16A) {
        // --- issue order matters: vmcnt is in-order. self -> idx -> bfr_self ->
        //     gather. Consuming bfr_self then only waits past the gathers' count.
        uint4 s0 = *(const uint4*)(atomsH + (size_t)(row0g + rr0) * NF + ch0);
        uint4 s1 = *(const uint4*)(atomsH + (size_t)(row0g + rr1) * NF + ch0);

        const int gr  = tid >> 3;                 // gather: 8 thr/row, 16 cols each
        const int gc  = (tid & 7) * 16;
        const int grr = min(gr, valid - 1);

        int idxs[DEG > 0 ? DEG : 1];
        if constexpr (DEG > 0) {
            const int* arow = adj + (size_t)(row0 + grr) * DEG;
#pragma unroll
            for (int j = 0; j < DEG; ++j) idxs[j] = arow[j];
        }

        // hoist self-half B-fragments (independent of LDS and of the gather)
        short8 bs[4][2];
        {
            const unsigned short* Wp = Wt + (size_t)wi_self * NF * NF;
#pragma unroll
            for (int kk = 0; kk < 4; ++kk)
#pragma unroll
                for (int nt = 0; nt < 2; ++nt)
                    bs[kk][nt] = *(const short8*)(Wp + (size_t)(col0 + nt * 16 + nb) * NF
                                                     + kk * 32 + kq);
        }

        if constexpr (DEG > 0) {
            // issue ALL gather loads; they stay in flight across the raw barrier
            uint4 ga[DEG], gb[DEG];
#pragma unroll
            for (int j = 0; j < DEG; ++j) {
                const unsigned short* base = atomsH + (size_t)idxs[j] * NF + gc;
                ga[j] = *(const uint4*)base;
                gb[j] = *(const uint4*)(base + 8);
            }

            // self -> LDS cols [0,128)
            *(uint4*)&sA[r0 * LDK2 + ch0] = s0;
            *(uint4*)&sA[r1 * LDK2 + ch0] = s1;
            lgkm_barrier();                       // gathers remain outstanding

            mma4_pre(bs, 0);                      // self-half GEMM hides gather latency

            float s[16];
#pragma unroll
            for (int i = 0; i < 16; ++i) s[i] = 0.f;
#pragma unroll
            for (int j = 0; j < DEG; ++j) { addu4(s, ga[j]); addu4(s + 8, gb[j]); }
            uint4 w0 = pack16B(make_float4(s[0], s[1], s[2], s[3]),
                               make_float4(s[4], s[5], s[6], s[7]));
            uint4 w1 = pack16B(make_float4(s[8], s[9], s[10], s[11]),
                               make_float4(s[12], s[13], s[14], s[15]));
            *(uint4*)&sA[gr * LDK2 + NF + gc]     = w0;   // rel -> cols [128,256)
            *(uint4*)&sA[gr * LDK2 + NF + gc + 8] = w1;
            lgkm_barrier();

            mma4_ld(wi_rel, NF);                  // rel-half GEMM
        } else {
            *(uint4*)&sA[r0 * LDK2 + ch0] = s0;
            *(uint4*)&sA[r1 * LDK2 + ch0] = s1;
            lgkm_barrier();
            mma4_pre(bs, 0);
        }
    } else {
        // ---- fp32 fallback: round-4 single-barrier structure ----
        const float4* sp0 = (const float4*)(atomsF + (size_t)(row0g + rr0) * NF + ch0);
        const float4* sp1 = (const float4*)(atomsF + (size_t)(row0g + rr1) * NF + ch0);
        float4 a0 = sp0[0], a1 = sp0[1], a2 = sp1[0], a3 = sp1[1];
        *(uint4*)&sA[r0 * LDK2 + ch0] = pack16B(a0, a1);
        *(uint4*)&sA[r1 * LDK2 + ch0] = pack16B(a2, a3);
        if constexpr (DEG > 0) {
            const int gr  = tid >> 3;
            const int gc  = (tid & 7) * 16;
            const int grr = min(gr, valid - 1);
            const int* arow = adj + (size_t)(row0 + grr) * DEG;
            int idxs[DEG];
#pragma unroll
            for (int j = 0; j < DEG; ++j) idxs[j] = arow[j];
            float s[16];
#pragma unroll
            for (int i = 0; i < 16; ++i) s[i] = 0.f;
            float4 q0, q1, q2, q3, n0, n1, n2, n3;
            {
                const float4* p = (const float4*)(atomsF + (size_t)idxs[0] * NF + gc);
                q0 = p[0]; q1 = p[1]; q2 = p[2]; q3 = p[3];
            }
#pragma unroll
            for (int j = 0; j < DEG; ++j) {
                if (j + 1 < DEG) {
                    const float4* p = (const float4*)(atomsF + (size_t)idxs[j + 1] * NF + gc);
                    n0 = p[0]; n1 = p[1]; n2 = p[2]; n3 = p[3];
                }
                s[0]  += q0.x; s[1]  += q0.y; s[2]  += q0.z; s[3]  += q0.w;
                s[4]  += q1.x; s[5]  += q1.y; s[6]  += q1.z; s[7]  += q1.w;
                s[8]  += q2.x; s[9]  += q2.y; s[10] += q2.z; s[11] += q2.w;
                s[12] += q3.x; s[13] += q3.y; s[14] += q3.z; s[15] += q3.w;
                q0 = n0; q1 = n1; q2 = n2; q3 = n3;
            }
            uint4 w0 = pack16B(make_float4(s[0], s[1], s[2], s[3]),
                               make_float4(s[4], s[5], s[6], s[7]));
            uint4 w1 = pack16B(make_float4(s[8], s[9], s[10], s[11]),
                               make_float4(s[12], s[13], s[14], s[15]));
            *(uint4*)&sA[gr * LDK2 + NF + gc]     = w0;
            *(uint4*)&sA[gr * LDK2 + NF + gc + 8] = w1;
        }
        __syncthreads();
        mma4_ld(wi_self, 0);
        if constexpr (DEG > 0) mma4_ld(wi_rel, NF);
    }

    // ---- epilogue: bias + nontemporal fp32 store (keep mirror in L3) ----
    float bias[2];
#pragma unroll
    for (int nt = 0; nt < 2; ++nt) {
        const int n = col0 + nt * 16 + nb;
        float bv = bvec[wi_self * NF + n];
        if (DEG > 0) bv += bvec[wi_rel * NF + n];
        bias[nt] = bv;
    }
    const int rq = (lane >> 4) * 4;
#pragma unroll
    for (int mt = 0; mt < 2; ++mt) {
#pragma unroll
        for (int reg = 0; reg < 4; ++reg) {
            const int r = mt * 16 + rq + reg;
            if (r < valid) {
                float* op = out + (size_t)(row0g + r) * NF;
#pragma unroll
                for (int nt = 0; nt < 2; ++nt)
                    __builtin_nontemporal_store(acc[mt][nt][reg] + bias[nt],
                                                op + col0 + nt * 16 + nb);
            }
        }
    }
}

template <bool BF16A>
__global__ __launch_bounds__(256) void fused_kernel(
    const float* __restrict__ atomsF, const unsigned short* __restrict__ atomsH,
    const unsigned short* __restrict__ Wt, const float* __restrict__ bvec,
    const int* __restrict__ adj1, const int* __restrict__ adj2,
    const int* __restrict__ adj3, const int* __restrict__ adj4,
    const int* __restrict__ adj5, const int* __restrict__ adj6,
    float* __restrict__ out)
{
    __shared__ unsigned short sA[32 * LDK2];   // 16896 B
    // deg-interleaved 1D grid: uniform work mix -> no deg-6 tail
    const int bid = blockIdx.x;
    const int deg = bid % 7, bx = bid / 7;
    switch (deg) {
        case 0: fused_work<0, BF16A>(atomsF, atomsH, Wt, bvec, nullptr, out, sA, bx); break;
        case 1: fused_work<1, BF16A>(atomsF, atomsH, Wt, bvec, adj1,    out, sA, bx); break;
        case 2: fused_work<2, BF16A>(atomsF, atomsH, Wt, bvec, adj2,    out, sA, bx); break;
        case 3: fused_work<3, BF16A>(atomsF, atomsH, Wt, bvec, adj3,    out, sA, bx); break;
        case 4: fused_work<4, BF16A>(atomsF, atomsH, Wt, bvec, adj4,    out, sA, bx); break;
        case 5: fused_work<5, BF16A>(atomsF, atomsH, Wt, bvec, adj5,    out, sA, bx); break;
        default: fused_work<6, BF16A>(atomsF, atomsH, Wt, bvec, adj6,   out, sA, bx); break;
    }
}

// ---- correctness fallback (tiny/absent workspace): fp32 exact, slow ----
__global__ __launch_bounds__(128) void naive_kernel(
    const float* __restrict__ atoms, const float* __restrict__ W,
    const float* __restrict__ b,
    const int* __restrict__ adj1, const int* __restrict__ adj2,
    const int* __restrict__ adj3, const int* __restrict__ adj4,
    const int* __restrict__ adj5, const int* __restrict__ adj6,
    float* __restrict__ out)
{
    const int i = blockIdx.x;
    const int deg = i / NPD, r = i - deg * NPD, n = threadIdx.x;
    __shared__ float selfr[NF], relr[NF];
    selfr[n] = atoms[(size_t)i * NF + n];
    float rv = 0.f;
    if (deg > 0) {
        const int* adjs[6] = {adj1, adj2, adj3, adj4, adj5, adj6};
        const int* adj = adjs[deg - 1];
        for (int j = 0; j < deg; ++j)
            rv += atoms[(size_t)adj[(size_t)r * deg + j] * NF + n];
    }
    relr[n] = rv;
    __syncthreads();
    const int ws  = (deg == 0) ? 12 : 2 * deg - 1;
    const int wrl = 2 * (deg - 1);
    float acc = b[ws * NF + n] + ((deg > 0) ? b[wrl * NF + n] : 0.f);
    for (int k = 0; k < NF; ++k) {
        acc += selfr[k] * W[(size_t)ws * NF * NF + (size_t)k * NF + n];
        if (deg > 0) acc += relr[k] * W[(size_t)wrl * NF * NF + (size_t)k * NF + n];
    }
    out[(size_t)i * NF + n] = acc;
}

extern "C" void kernel_launch(void* const* d_in, const int* in_sizes, int n_in,
                              void* d_out, int out_size, void* d_ws, size_t ws_size,
                              hipStream_t stream) {
    const float* atoms = (const float*)d_in[0];
    const float* W     = (const float*)d_in[1];
    const float* b     = (const float*)d_in[2];
    // d_in[3] = deg_slice (static, unused)
    const int* adj1 = (const int*)d_in[4];
    const int* adj2 = (const int*)d_in[5];
    const int* adj3 = (const int*)d_in[6];
    const int* adj4 = (const int*)d_in[7];
    const int* adj5 = (const int*)d_in[8];
    const int* adj6 = (const int*)d_in[9];

    const size_t wt_bytes = (size_t)13 * NF * NF * sizeof(unsigned short);            // 425,984
    const size_t at_bytes = (size_t)NPD * (MAXDEG + 1) * NF * sizeof(unsigned short); // 53.76 MB
    const int gx = (NPD + 31) / 32;   // 938 row-tiles per degree

    if (ws_size >= wt_bytes + at_bytes) {
        unsigned short* Wt     = (unsigned short*)d_ws;
        unsigned short* atomsH = (unsigned short*)((char*)d_ws + wt_bytes);
        prep_kernel<<<WT_BLOCKS + CVT8_BLOCKS, 256, 0, stream>>>(atoms, W, atomsH, Wt);
        fused_kernel<true><<<gx * 7, 256, 0, stream>>>(
            atoms, atomsH, Wt, b, adj1, adj2, adj3, adj4, adj5, adj6, (float*)d_out);
    } else if (ws_size >= wt_bytes) {
        unsigned short* Wt = (unsigned short*)d_ws;
        prep_kernel<<<WT_BLOCKS, 256, 0, stream>>>(atoms, W, nullptr, Wt);  // wt only
        fused_kernel<false><<<gx * 7, 256, 0, stream>>>(
            atoms, nullptr, Wt, b, adj1, adj2, adj3, adj4, adj5, adj6, (float*)d_out);
    } else {
        naive_kernel<<<NPD * (MAXDEG + 1), NF, 0, stream>>>(
            atoms, W, b, adj1, adj2, adj3, adj4, adj5, adj6, (float*)d_out);
    }
}

// Round 6
// 258.861 us; speedup vs baseline: 1.1570x; 1.0222x over previous
//
#include <hip/hip_runtime.h>
#include <hip/hip_bf16.h>

#define NPD 30000        // atoms per degree bucket
#define NF  128          // feature dim == filter dim
#define MAXDEG 6
#define LDK2 264         // padded K=256 LDS leading dim (bf16): 528 B row stride

#define WT_BLOCKS   208  // 13 matrices x 16 (32x32) tiles
#define CVT8_BLOCKS 1641 // ceil(210000*128/8 / (256*8))

typedef __attribute__((ext_vector_type(8))) short short8;   // 8 x bf16 (4 VGPRs)
typedef __attribute__((ext_vector_type(4))) float floatx4;  // MFMA accumulator / NT loads

__device__ __forceinline__ unsigned short f2bf(float f) {
    __hip_bfloat16 h = __float2bfloat16(f);
    return __builtin_bit_cast(unsigned short, h);
}
__device__ __forceinline__ float bf2f(unsigned short u) {
    unsigned v = ((unsigned)u) << 16; return __builtin_bit_cast(float, v);
}
__device__ __forceinline__ uint4 pack16B(float4 a, float4 b) {
    uint4 v;
    v.x = (unsigned)f2bf(a.x) | ((unsigned)f2bf(a.y) << 16);
    v.y = (unsigned)f2bf(a.z) | ((unsigned)f2bf(a.w) << 16);
    v.z = (unsigned)f2bf(b.x) | ((unsigned)f2bf(b.y) << 16);
    v.w = (unsigned)f2bf(b.z) | ((unsigned)f2bf(b.w) << 16);
    return v;
}
__device__ __forceinline__ uint4 pack16Bv(floatx4 a, floatx4 b) {
    uint4 v;
    v.x = (unsigned)f2bf(a.x) | ((unsigned)f2bf(a.y) << 16);
    v.y = (unsigned)f2bf(a.z) | ((unsigned)f2bf(a.w) << 16);
    v.z = (unsigned)f2bf(b.x) | ((unsigned)f2bf(b.y) << 16);
    v.w = (unsigned)f2bf(b.z) | ((unsigned)f2bf(b.w) << 16);
    return v;
}
__device__ __forceinline__ void addu4(float* s, uint4 h) {
    s[0] += bf2f((unsigned short)h.x); s[1] += bf2f((unsigned short)(h.x >> 16));
    s[2] += bf2f((unsigned short)h.y); s[3] += bf2f((unsigned short)(h.y >> 16));
    s[4] += bf2f((unsigned short)h.z); s[5] += bf2f((unsigned short)(h.z >> 16));
    s[6] += bf2f((unsigned short)h.w); s[7] += bf2f((unsigned short)(h.w >> 16));
}

// lgkmcnt-only barrier: LDS writes visible, but global loads stay in flight
// (__syncthreads drains vmcnt(0), which would kill the gather overlap).
__device__ __forceinline__ void lgkm_barrier() {
    asm volatile("s_waitcnt lgkmcnt(0)" ::: "memory");
    __builtin_amdgcn_s_barrier();
}

// ---- prep: wt tiles (bx < 208) + fp32->bf16 atoms mirror (grid-stride x8) ----
__global__ __launch_bounds__(256) void prep_kernel(
    const float* __restrict__ atoms, const float* __restrict__ W,
    unsigned short* __restrict__ atomsH, unsigned short* __restrict__ Wt)
{
    __shared__ unsigned short t[32][33];
    const int bx = blockIdx.x;
    if (bx < WT_BLOCKS) {                         // W[a][k][n] -> Wt[a][n][k] bf16
        const int a  = bx >> 4;
        const int k0 = ((bx >> 2) & 3) * 32, n0 = (bx & 3) * 32;
        const int tx = threadIdx.x & 31, ty = threadIdx.x >> 5;
        const float*    Wp  = W  + (size_t)a * NF * NF;
        unsigned short* Wtp = Wt + (size_t)a * NF * NF;
#pragma unroll
        for (int i = 0; i < 32; i += 8)
            t[ty + i][tx] = f2bf(Wp[(size_t)(k0 + ty + i) * NF + (n0 + tx)]);
        __syncthreads();
#pragma unroll
        for (int i = 0; i < 32; i += 8)
            Wtp[(size_t)(n0 + ty + i) * NF + (k0 + tx)] = t[tx][ty + i];
    } else {
        const size_t n8   = (size_t)NPD * (MAXDEG + 1) * NF / 8;   // 3,360,000 uint4s
        const size_t base = (size_t)(bx - WT_BLOCKS) * 2048 + threadIdx.x;
#pragma unroll
        for (int it = 0; it < 8; ++it) {
            const size_t i = base + (size_t)it * 256;
            if (i < n8) {
                const floatx4* p = (const floatx4*)(atoms + i * 8);
                floatx4 a = __builtin_nontemporal_load(p);      // fp32 dead after this
                floatx4 b = __builtin_nontemporal_load(p + 1);
                ((uint4*)atomsH)[i] = pack16Bv(a, b);           // plain store: L2/L3-warm
            }
        }
    }
}

// ---- fused, 2-tile pipelined: 64 rows/block through one 32-row LDS buffer ----
template <int DEG, bool BF16A>
__device__ __forceinline__ void fused_work(
    const float* __restrict__ atomsF, const unsigned short* __restrict__ atomsH,
    const unsigned short* __restrict__ Wt, const float* __restrict__ bvec,
    const int* __restrict__ adj, float* __restrict__ out,
    unsigned short* __restrict__ sA, int bx)
{
    const int tid  = threadIdx.x;
    const int lane = tid & 63, wave = tid >> 6;
    const int nb = lane & 15;
    const int kq = (lane >> 4) * 8;
    const int col0 = wave * 32;
    const int row0 = bx * 64;
    const int v0 = min(32, NPD - row0);
    const int v1 = min(32, NPD - row0 - 32);      // may be <=0 on the last block
    const int row0g = DEG * NPD + row0;
    const int wi_self = (DEG == 0) ? 12 : (2 * DEG - 1);
    const int wi_rel  = (DEG > 0) ? 2 * (DEG - 1) : 0;

    // self-stage geometry: 512 chunks of 8 cols; thread covers chunk tid, tid+256
    const int r0 = tid >> 4,  ch0 = (tid & 15) * 8;
    const int r1 = r0 + 16;
    // gather geometry: 8 thr/row, 16 cols each
    const int gr = tid >> 3,  gc = (tid & 7) * 16;

    floatx4 acc[2][2];
    auto zacc = [&]() {
#pragma unroll
        for (int i = 0; i < 2; i++)
#pragma unroll
            for (int j = 0; j < 2; j++) acc[i][j] = (floatx4){0.f, 0.f, 0.f, 0.f};
    };
    auto mma4_pre = [&](const short8 bs[4][2], int aoff) {
#pragma unroll
        for (int kk = 0; kk < 4; ++kk) {
            short8 af[2];
#pragma unroll
            for (int mt = 0; mt < 2; ++mt)
                af[mt] = *(const short8*)&sA[(mt * 16 + nb) * LDK2 + aoff + kk * 32 + kq];
#pragma unroll
            for (int mt = 0; mt < 2; ++mt)
#pragma unroll
                for (int nt = 0; nt < 2; ++nt)
                    acc[mt][nt] = __builtin_amdgcn_mfma_f32_16x16x32_bf16(
                        af[mt], bs[kk][nt], acc[mt][nt], 0, 0, 0);
        }
    };
    auto mma4_ld = [&](int wi, int aoff) {
        const unsigned short* Wp = Wt + (size_t)wi * NF * NF;
#pragma unroll
        for (int kk = 0; kk < 4; ++kk) {
            short8 bfr[2];
#pragma unroll
            for (int nt = 0; nt < 2; ++nt)
                bfr[nt] = *(const short8*)(Wp + (size_t)(col0 + nt * 16 + nb) * NF
                                              + kk * 32 + kq);
            short8 af[2];
#pragma unroll
            for (int mt = 0; mt < 2; ++mt)
                af[mt] = *(const short8*)&sA[(mt * 16 + nb) * LDK2 + aoff + kk * 32 + kq];
#pragma unroll
            for (int mt = 0; mt < 2; ++mt)
#pragma unroll
                for (int nt = 0; nt < 2; ++nt)
                    acc[mt][nt] = __builtin_amdgcn_mfma_f32_16x16x32_bf16(
                        af[mt], bfr[nt], acc[mt][nt], 0, 0, 0);
        }
    };
    // bias is identical for both tiles: compute once
    float bias[2];
#pragma unroll
    for (int nt = 0; nt < 2; ++nt) {
        const int n = col0 + nt * 16 + nb;
        float bv = bvec[wi_self * NF + n];
        if (DEG > 0) bv += bvec[wi_rel * NF + n];
        bias[nt] = bv;
    }
    const int rq = (lane >> 4) * 4;
    auto epilogue = [&](int vlim, int toff) {
#pragma unroll
        for (int mt = 0; mt < 2; ++mt) {
#pragma unroll
            for (int reg = 0; reg < 4; ++reg) {
                const int r = mt * 16 + rq + reg;
                if (r < vlim) {
                    float* op = out + (size_t)(row0g + toff + r) * NF;
#pragma unroll
                    for (int nt = 0; nt < 2; ++nt)
                        __builtin_nontemporal_store(acc[mt][nt][reg] + bias[nt],
                                                    op + col0 + nt * 16 + nb);
                }
            }
        }
    };

    if constexpr (BF16A) {
        // ---- tile0 top issues (order matters: vmcnt is in-order) ----
        uint4 s0a = *(const uint4*)(atomsH + (size_t)(row0g + min(r0, v0 - 1)) * NF + ch0);
        uint4 s0b = *(const uint4*)(atomsH + (size_t)(row0g + min(r1, v0 - 1)) * NF + ch0);

        int idx0[DEG > 0 ? DEG : 1];
        if constexpr (DEG > 0) {
            const int* arow = adj + (size_t)(row0 + min(gr, v0 - 1)) * DEG;
#pragma unroll
            for (int j = 0; j < DEG; ++j) idx0[j] = arow[j];
        }
        // hoisted self-B fragments: amortized over BOTH tiles
        short8 bs[4][2];
        {
            const unsigned short* Wp = Wt + (size_t)wi_self * NF * NF;
#pragma unroll
            for (int kk = 0; kk < 4; ++kk)
#pragma unroll
                for (int nt = 0; nt < 2; ++nt)
                    bs[kk][nt] = *(const short8*)(Wp + (size_t)(col0 + nt * 16 + nb) * NF
                                                     + kk * 32 + kq);
        }

        if constexpr (DEG > 0) {
            uint4 ga[DEG], gb[DEG];
#pragma unroll
            for (int j = 0; j < DEG; ++j) {          // gather0: stays in flight
                const unsigned short* base = atomsH + (size_t)idx0[j] * NF + gc;
                ga[j] = *(const uint4*)base;
                gb[j] = *(const uint4*)(base + 8);
            }
            *(uint4*)&sA[r0 * LDK2 + ch0] = s0a;     // self0 -> LDS
            *(uint4*)&sA[r1 * LDK2 + ch0] = s0b;
            lgkm_barrier();
            zacc();
            mma4_pre(bs, 0);                          // self-GEMM0 hides gather0

            float s[16];
#pragma unroll
            for (int i = 0; i < 16; ++i) s[i] = 0.f;
#pragma unroll
            for (int j = 0; j < DEG; ++j) { addu4(s, ga[j]); addu4(s + 8, gb[j]); }
            *(uint4*)&sA[gr * LDK2 + NF + gc]     = pack16B(
                make_float4(s[0], s[1], s[2], s[3]), make_float4(s[4], s[5], s[6], s[7]));
            *(uint4*)&sA[gr * LDK2 + NF + gc + 8] = pack16B(
                make_float4(s[8], s[9], s[10], s[11]), make_float4(s[12], s[13], s[14], s[15]));

            // ---- tile1 issues: gather0 regs just died; g1/s1 fly under
            //      rel-GEMM0 + epilogue0 + stage1 ----
            uint4 s1a, s1b;
            int idx1[DEG];
            if (v1 > 0) {
                s1a = *(const uint4*)(atomsH + (size_t)(row0g + 32 + min(r0, v1 - 1)) * NF + ch0);
                s1b = *(const uint4*)(atomsH + (size_t)(row0g + 32 + min(r1, v1 - 1)) * NF + ch0);
                const int* arow1 = adj + (size_t)(row0 + 32 + min(gr, v1 - 1)) * DEG;
#pragma unroll
                for (int j = 0; j < DEG; ++j) idx1[j] = arow1[j];
            }
            lgkm_barrier();
            mma4_ld(wi_rel, NF);                      // rel-GEMM0
            epilogue(v0, 0);

            if (v1 > 0) {                             // uniform across block
                uint4 ga1[DEG], gb1[DEG];
#pragma unroll
                for (int j = 0; j < DEG; ++j) {       // gather1: in flight across barriers
                    const unsigned short* base = atomsH + (size_t)idx1[j] * NF + gc;
                    ga1[j] = *(const uint4*)base;
                    gb1[j] = *(const uint4*)(base + 8);
                }
                lgkm_barrier();                       // all waves done reading tile0 LDS
                *(uint4*)&sA[r0 * LDK2 + ch0] = s1a;  // stage1 (waits s1 only; g1 older,
                *(uint4*)&sA[r1 * LDK2 + ch0] = s1b;  //  so it completes too - fine)
                lgkm_barrier();
                zacc();
                mma4_pre(bs, 0);                      // self-GEMM1 hides gather1 tail

                float s2[16];
#pragma unroll
                for (int i = 0; i < 16; ++i) s2[i] = 0.f;
#pragma unroll
                for (int j = 0; j < DEG; ++j) { addu4(s2, ga1[j]); addu4(s2 + 8, gb1[j]); }
                *(uint4*)&sA[gr * LDK2 + NF + gc]     = pack16B(
                    make_float4(s2[0], s2[1], s2[2], s2[3]),
                    make_float4(s2[4], s2[5], s2[6], s2[7]));
                *(uint4*)&sA[gr * LDK2 + NF + gc + 8] = pack16B(
                    make_float4(s2[8], s2[9], s2[10], s2[11]),
                    make_float4(s2[12], s2[13], s2[14], s2[15]));
                lgkm_barrier();
                mma4_ld(wi_rel, NF);                  // rel-GEMM1
                epilogue(v1, 32);
            }
        } else {
            // DEG == 0: two self-only tiles
            uint4 s1a, s1b;
            if (v1 > 0) {
                s1a = *(const uint4*)(atomsH + (size_t)(row0g + 32 + min(r0, v1 - 1)) * NF + ch0);
                s1b = *(const uint4*)(atomsH + (size_t)(row0g + 32 + min(r1, v1 - 1)) * NF + ch0);
            }
            *(uint4*)&sA[r0 * LDK2 + ch0] = s0a;
            *(uint4*)&sA[r1 * LDK2 + ch0] = s0b;
            lgkm_barrier();
            zacc();
            mma4_pre(bs, 0);
            epilogue(v0, 0);
            if (v1 > 0) {
                lgkm_barrier();
                *(uint4*)&sA[r0 * LDK2 + ch0] = s1a;
                *(uint4*)&sA[r1 * LDK2 + ch0] = s1b;
                lgkm_barrier();
                zacc();
                mma4_pre(bs, 0);
                epilogue(v1, 32);
            }
        }
    } else {
        // ---- fp32 fallback: simple 2x single-barrier structure ----
        for (int t = 0; t < 2; ++t) {
            const int vt = (t == 0) ? v0 : v1;
            if (vt <= 0) break;
            const int toff = t * 32;
            if (t) __syncthreads();
            const float4* sp0 = (const float4*)(atomsF + (size_t)(row0g + toff + min(r0, vt - 1)) * NF + ch0);
            const float4* sp1 = (const float4*)(atomsF + (size_t)(row0g + toff + min(r1, vt - 1)) * NF + ch0);
            float4 a0 = sp0[0], a1 = sp0[1], a2 = sp1[0], a3 = sp1[1];
            *(uint4*)&sA[r0 * LDK2 + ch0] = pack16B(a0, a1);
            *(uint4*)&sA[r1 * LDK2 + ch0] = pack16B(a2, a3);
            if constexpr (DEG > 0) {
                const int* arow = adj + (size_t)(row0 + toff + min(gr, vt - 1)) * DEG;
                int idxs[DEG];
#pragma unroll
                for (int j = 0; j < DEG; ++j) idxs[j] = arow[j];
                float s[16];
#pragma unroll
                for (int i = 0; i < 16; ++i) s[i] = 0.f;
#pragma unroll
                for (int j = 0; j < DEG; ++j) {
                    const float4* p = (const float4*)(atomsF + (size_t)idxs[j] * NF + gc);
                    float4 q0 = p[0], q1 = p[1], q2 = p[2], q3 = p[3];
                    s[0]  += q0.x; s[1]  += q0.y; s[2]  += q0.z; s[3]  += q0.w;
                    s[4]  += q1.x; s[5]  += q1.y; s[6]  += q1.z; s[7]  += q1.w;
                    s[8]  += q2.x; s[9]  += q2.y; s[10] += q2.z; s[11] += q2.w;
                    s[12] += q3.x; s[13] += q3.y; s[14] += q3.z; s[15] += q3.w;
                }
                *(uint4*)&sA[gr * LDK2 + NF + gc]     = pack16B(
                    make_float4(s[0], s[1], s[2], s[3]), make_float4(s[4], s[5], s[6], s[7]));
                *(uint4*)&sA[gr * LDK2 + NF + gc + 8] = pack16B(
                    make_float4(s[8], s[9], s[10], s[11]), make_float4(s[12], s[13], s[14], s[15]));
            }
            __syncthreads();
            zacc();
            mma4_ld(wi_self, 0);
            if constexpr (DEG > 0) mma4_ld(wi_rel, NF);
            epilogue(vt, toff);
        }
    }
}

template <bool BF16A>
__global__ __launch_bounds__(256) void fused_kernel(
    const float* __restrict__ atomsF, const unsigned short* __restrict__ atomsH,
    const unsigned short* __restrict__ Wt, const float* __restrict__ bvec,
    const int* __restrict__ adj1, const int* __restrict__ adj2,
    const int* __restrict__ adj3, const int* __restrict__ adj4,
    const int* __restrict__ adj5, const int* __restrict__ adj6,
    float* __restrict__ out)
{
    __shared__ unsigned short sA[32 * LDK2];   // 16896 B, reused by both tiles
    // deg-interleaved 1D grid: uniform work mix -> no deg-6 tail
    const int bid = blockIdx.x;
    const int deg = bid % 7, bx = bid / 7;
    switch (deg) {
        case 0: fused_work<0, BF16A>(atomsF, atomsH, Wt, bvec, nullptr, out, sA, bx); break;
        case 1: fused_work<1, BF16A>(atomsF, atomsH, Wt, bvec, adj1,    out, sA, bx); break;
        case 2: fused_work<2, BF16A>(atomsF, atomsH, Wt, bvec, adj2,    out, sA, bx); break;
        case 3: fused_work<3, BF16A>(atomsF, atomsH, Wt, bvec, adj3,    out, sA, bx); break;
        case 4: fused_work<4, BF16A>(atomsF, atomsH, Wt, bvec, adj4,    out, sA, bx); break;
        case 5: fused_work<5, BF16A>(atomsF, atomsH, Wt, bvec, adj5,    out, sA, bx); break;
        default: fused_work<6, BF16A>(atomsF, atomsH, Wt, bvec, adj6,   out, sA, bx); break;
    }
}

// ---- correctness fallback (tiny/absent workspace): fp32 exact, slow ----
__global__ __launch_bounds__(128) void naive_kernel(
    const float* __restrict__ atoms, const float* __restrict__ W,
    const float* __restrict__ b,
    const int* __restrict__ adj1, const int* __restrict__ adj2,
    const int* __restrict__ adj3, const int* __restrict__ adj4,
    const int* __restrict__ adj5, const int* __restrict__ adj6,
    float* __restrict__ out)
{
    const int i = blockIdx.x;
    const int deg = i / NPD, r = i - deg * NPD, n = threadIdx.x;
    __shared__ float selfr[NF], relr[NF];
    selfr[n] = atoms[(size_t)i * NF + n];
    float rv = 0.f;
    if (deg > 0) {
        const int* adjs[6] = {adj1, adj2, adj3, adj4, adj5, adj6};
        const int* adj = adjs[deg - 1];
        for (int j = 0; j < deg; ++j)
            rv += atoms[(size_t)adj[(size_t)r * deg + j] * NF + n];
    }
    relr[n] = rv;
    __syncthreads();
    const int ws  = (deg == 0) ? 12 : 2 * deg - 1;
    const int wrl = 2 * (deg - 1);
    float acc = b[ws * NF + n] + ((deg > 0) ? b[wrl * NF + n] : 0.f);
    for (int k = 0; k < NF; ++k) {
        acc += selfr[k] * W[(size_t)ws * NF * NF + (size_t)k * NF + n];
        if (deg > 0) acc += relr[k] * W[(size_t)wrl * NF * NF + (size_t)k * NF + n];
    }
    out[(size_t)i * NF + n] = acc;
}

extern "C" void kernel_launch(void* const* d_in, const int* in_sizes, int n_in,
                              void* d_out, int out_size, void* d_ws, size_t ws_size,
                              hipStream_t stream) {
    const float* atoms = (const float*)d_in[0];
    const float* W     = (const float*)d_in[1];
    const float* b     = (const float*)d_in[2];
    // d_in[3] = deg_slice (static, unused)
    const int* adj1 = (const int*)d_in[4];
    const int* adj2 = (const int*)d_in[5];
    const int* adj3 = (const int*)d_in[6];
    const int* adj4 = (const int*)d_in[7];
    const int* adj5 = (const int*)d_in[8];
    const int* adj6 = (const int*)d_in[9];

    const size_t wt_bytes = (size_t)13 * NF * NF * sizeof(unsigned short);            // 425,984
    const size_t at_bytes = (size_t)NPD * (MAXDEG + 1) * NF * sizeof(unsigned short); // 53.76 MB
    const int gxB = (NPD + 63) / 64;   // 469 64-row blocks per degree

    if (ws_size >= wt_bytes + at_bytes) {
        unsigned short* Wt     = (unsigned short*)d_ws;
        unsigned short* atomsH = (unsigned short*)((char*)d_ws + wt_bytes);
        prep_kernel<<<WT_BLOCKS + CVT8_BLOCKS, 256, 0, stream>>>(atoms, W, atomsH, Wt);
        fused_kernel<true><<<gxB * 7, 256, 0, stream>>>(
            atoms, atomsH, Wt, b, adj1, adj2, adj3, adj4, adj5, adj6, (float*)d_out);
    } else if (ws_size >= wt_bytes) {
        unsigned short* Wt = (unsigned short*)d_ws;
        prep_kernel<<<WT_BLOCKS, 256, 0, stream>>>(atoms, W, nullptr, Wt);  // wt only
        fused_kernel<false><<<gxB * 7, 256, 0, stream>>>(
            atoms, nullptr, Wt, b, adj1, adj2, adj3, adj4, adj5, adj6, (float*)d_out);
    } else {
        naive_kernel<<<NPD * (MAXDEG + 1), NF, 0, stream>>>(
            atoms, W, b, adj1, adj2, adj3, adj4, adj5, adj6, (float*)d_out);
    }
}